// Round 9
// baseline (38.638 us; speedup 1.0000x reference)
//
#include <hip/hip_runtime.h>

namespace {
constexpr int Bn = 4, Dn = 4, Hn = 768, Wn = 768;
constexpr int HWc = Hn * Wn;                       // 589824
constexpr size_t DHWc = (size_t)Dn * HWc;          // 2359296
constexpr float BONUS = 10.0f;
}

typedef float floatx4 __attribute__((ext_vector_type(4)));

__device__ __forceinline__ void stnt(float* p, float a, float b, float c, float d) {
    floatx4 v = {a, b, c, d};
    __builtin_nontemporal_store(v, reinterpret_cast<floatx4*>(p));
}

// Exact round-5 structure (one (b,h) row per block, ALL 36 loads issued
// up-front for max MLP, d in {1,2} solve only) + nontemporal output stores.
__global__ __launch_bounds__(192) void cqi3d(const float* __restrict__ x,
                                             float* __restrict__ coords,
                                             float* __restrict__ ymax) {
#pragma clang fp contract(off)
    int id = blockIdx.x;
    id = (id & 7) * ((Hn * Bn) >> 3) + (id >> 3);   // XCD-contiguous swizzle
    const int h = id % Hn;
    const int b = id / Hn;
    const int t = threadIdx.x;
    const int w0 = t << 2;

    const float* base = x + (size_t)b * DHWc;
    float* cb = coords + (size_t)b * 3 * DHWc;
    float* yb = ymax + (size_t)b * DHWc;

    const float fw0 = (float)w0, fw1 = (float)(w0 + 1), fw2 = (float)(w0 + 2), fw3 = (float)(w0 + 3);
    const float fh = (float)h;

    if (h == 0 || h == Hn - 1) {
        // boundary row: every voxel trivial; only center-row loads needed
#pragma unroll
        for (int d = 0; d < 4; ++d) {
            const size_t sp = (size_t)d * HWc + (size_t)h * Wn + (size_t)w0;
            const float4 q = *reinterpret_cast<const float4*>(base + sp);
            stnt(cb + sp,            (float)d, (float)d, (float)d, (float)d);
            stnt(cb + DHWc + sp,     fw0, fw1, fw2, fw3);
            stnt(cb + 2 * DHWc + sp, fh, fh, fh, fh);
            stnt(yb + sp,            q.x, q.y, q.z, q.w);
        }
        return;
    }

    const int wl = (w0 == 0) ? 0 : w0 - 1;
    const int wr = (w0 + 4 < Wn) ? w0 + 4 : Wn - 1;
    const int hz[3] = {h - 1, h, h + 1};

    // v[a][dd][c]: a = h-axis, dd = d-slice, c: 0 = w0-1, 1..4 = w0..w0+3, 5 = w0+4
    float v[3][4][6];
#pragma unroll
    for (int a = 0; a < 3; ++a) {
#pragma unroll
        for (int dd = 0; dd < 4; ++dd) {
            const float* ph = base + (size_t)dd * HWc + (size_t)hz[a] * Wn;
            const float4 q = *reinterpret_cast<const float4*>(ph + w0);
            v[a][dd][0] = ph[wl];
            v[a][dd][1] = q.x;
            v[a][dd][2] = q.y;
            v[a][dd][3] = q.z;
            v[a][dd][4] = q.w;
            v[a][dd][5] = ph[wr];
        }
    }

    // d = 0 and d = 3: trivial (strict NMS impossible vs replicated self)
    {
        const size_t sp0 = (size_t)h * Wn + (size_t)w0;
        stnt(cb + sp0,            0.f, 0.f, 0.f, 0.f);
        stnt(cb + DHWc + sp0,     fw0, fw1, fw2, fw3);
        stnt(cb + 2 * DHWc + sp0, fh, fh, fh, fh);
        stnt(yb + sp0,            v[1][0][1], v[1][0][2], v[1][0][3], v[1][0][4]);
        const size_t sp3 = 3 * (size_t)HWc + sp0;
        stnt(cb + sp3,            3.f, 3.f, 3.f, 3.f);
        stnt(cb + DHWc + sp3,     fw0, fw1, fw2, fw3);
        stnt(cb + 2 * DHWc + sp3, fh, fh, fh, fh);
        stnt(yb + sp3,            v[1][3][1], v[1][3][2], v[1][3][3], v[1][3][4]);
    }

    // d = 1, 2: full NMS + quadratic interpolation (bit-identical to round 5)
#pragma unroll
    for (int d = 1; d <= 2; ++d) {
        const int s0 = d - 1;
        const int s2 = d + 1;
        float colNC[6], cmax[6];
#pragma unroll
        for (int c = 0; c < 6; ++c) {
            float m = v[0][s0][c];
            m = fmaxf(m, v[1][s0][c]);
            m = fmaxf(m, v[2][s0][c]);
            m = fmaxf(m, v[0][d][c]);
            m = fmaxf(m, v[2][d][c]);
            m = fmaxf(m, v[0][s2][c]);
            m = fmaxf(m, v[1][s2][c]);
            m = fmaxf(m, v[2][s2][c]);
            colNC[c] = m;
            cmax[c] = fmaxf(m, v[1][d][c]);
        }

        float outz[4], outx[4], outy[4], outv[4];
#pragma unroll
        for (int j = 0; j < 4; ++j) {
            const int cc = j + 1;
            const float xc = v[1][d][cc];
            const float m = fmaxf(fmaxf(cmax[cc - 1], cmax[cc + 1]), fmaxf(colNC[cc], 0.0f));
            const bool nms = xc > m;

            const float gx  = 0.5f * (v[1][d][cc + 1] - v[1][d][cc - 1]);
            const float gy  = 0.5f * (v[2][d][cc] - v[0][d][cc]);
            const float gs  = 0.5f * (v[1][s2][cc] - v[1][s0][cc]);
            const float dxx = v[1][d][cc + 1] - 2.0f * xc + v[1][d][cc - 1];
            const float dyy = v[2][d][cc] - 2.0f * xc + v[0][d][cc];
            const float dss = v[1][s2][cc] - 2.0f * xc + v[1][s0][cc];
            const float dxy =  0.25f * (v[2][d][cc + 1] - v[2][d][cc - 1] - v[0][d][cc + 1] + v[0][d][cc - 1]);
            const float dys = -0.25f * (v[2][s2][cc] - v[0][s2][cc] - v[2][s0][cc] + v[0][s0][cc]);
            const float dxs = -0.25f * (v[1][s2][cc + 1] - v[1][s2][cc - 1] - v[1][s0][cc + 1] + v[1][s0][cc - 1]);

            const float cf00 = dyy * dss - dys * dys;
            const float cf01 = dxy * dss - dys * dxs;
            const float cf02 = dxy * dys - dyy * dxs;
            const float det  = dxx * cf00 - dxy * cf01 + dxs * cf02;
            const bool solved = fabsf(det) > 0.0f;
            const float sd = solved ? det : 1.0f;

            const float t0 = gy * dss - dys * gs;
            const float sx = (gx * cf00 - dxy * t0 + dxs * (gy * dys - dyy * gs)) / sd;
            const float sy = (dxx * t0 - gx * cf01 + dxs * (dxy * gs - gy * dxs)) / sd;
            const float ss = (dxx * (dyy * gs - gy * dys) - dxy * (dxy * gs - gy * dxs) + gx * cf02) / sd;

            const bool valid = nms && solved;
            float dxv = valid ? -sx : 0.0f;
            float dyv = valid ? -sy : 0.0f;
            float dsv = valid ? -ss : 0.0f;
            const float mx = fmaxf(fmaxf(fabsf(dxv), fabsf(dyv)), fabsf(dsv));
            if (mx > 0.7f) { dxv = 0.0f; dyv = 0.0f; dsv = 0.0f; }

            const float dy_ = 0.5f * (gx * dxv + gy * dyv + gs * dsv);
            float y = xc + dy_;
            if (valid) y += BONUS;

            outz[j] = (float)d + dsv;
            outx[j] = (float)(w0 + j) + dxv;
            outy[j] = fh + dyv;
            outv[j] = y;
        }

        const size_t sp = (size_t)d * HWc + (size_t)h * Wn + (size_t)w0;
        stnt(cb + sp,            outz[0], outz[1], outz[2], outz[3]);
        stnt(cb + DHWc + sp,     outx[0], outx[1], outx[2], outx[3]);
        stnt(cb + 2 * DHWc + sp, outy[0], outy[1], outy[2], outy[3]);
        stnt(yb + sp,            outv[0], outv[1], outv[2], outv[3]);
    }
}

extern "C" void kernel_launch(void* const* d_in, const int* in_sizes, int n_in,
                              void* d_out, int out_size, void* d_ws, size_t ws_size,
                              hipStream_t stream) {
    const float* x = (const float*)d_in[0];
    float* out = (float*)d_out;
    float* coords = out;                          // (B,1,3,D,H,W) flat
    float* ymaxp  = out + (size_t)Bn * 3 * DHWc;  // (B,1,D,H,W) flat
    cqi3d<<<dim3(Hn * Bn), dim3(192, 1, 1), 0, stream>>>(x, coords, ymaxp);
}

// Round 10
// 34.725 us; speedup vs baseline: 1.1127x; 1.1127x over previous
//
#include <hip/hip_runtime.h>

namespace {
constexpr int Bn = 4, Dn = 4, Hn = 768, Wn = 768;
constexpr int HWc = Hn * Wn;                       // 589824
constexpr size_t DHWc = (size_t)Dn * HWc;          // 2359296
constexpr float BONUS = 10.0f;
}

// Best configuration (round 5, 34.6 us): one thread = 4-wide w window x all 4
// d slices; ALL 36 loads issued up-front (max MLP); solve only for d in {1,2}
// (replicate-pad + strict '>' makes maxima impossible at d=0/3 and boundary
// h/w); regular (cached) float4 stores — NT stores measured 4 us slower.
__global__ __launch_bounds__(192) void cqi3d(const float* __restrict__ x,
                                             float* __restrict__ coords,
                                             float* __restrict__ ymax) {
#pragma clang fp contract(off)
    int id = blockIdx.x;
    id = (id & 7) * ((Hn * Bn) >> 3) + (id >> 3);   // XCD-contiguous swizzle
    const int h = id % Hn;
    const int b = id / Hn;
    const int t = threadIdx.x;
    const int w0 = t << 2;

    const float* base = x + (size_t)b * DHWc;
    float* cb = coords + (size_t)b * 3 * DHWc;
    float* yb = ymax + (size_t)b * DHWc;

    const float4 cz0 = make_float4(0.f, 0.f, 0.f, 0.f);
    const float4 cz3 = make_float4(3.f, 3.f, 3.f, 3.f);
    const float4 cx  = make_float4((float)w0, (float)(w0 + 1), (float)(w0 + 2), (float)(w0 + 3));
    const float4 cy  = make_float4((float)h, (float)h, (float)h, (float)h);

    if (h == 0 || h == Hn - 1) {
        // boundary row: every voxel trivial; only center-row loads needed
#pragma unroll
        for (int d = 0; d < 4; ++d) {
            const size_t sp = (size_t)d * HWc + (size_t)h * Wn + (size_t)w0;
            const float4 q = *reinterpret_cast<const float4*>(base + sp);
            *reinterpret_cast<float4*>(cb + sp)            = make_float4((float)d, (float)d, (float)d, (float)d);
            *reinterpret_cast<float4*>(cb + DHWc + sp)     = cx;
            *reinterpret_cast<float4*>(cb + 2 * DHWc + sp) = cy;
            *reinterpret_cast<float4*>(yb + sp)            = q;
        }
        return;
    }

    const int wl = (w0 == 0) ? 0 : w0 - 1;
    const int wr = (w0 + 4 < Wn) ? w0 + 4 : Wn - 1;
    const int hz[3] = {h - 1, h, h + 1};

    // v[a][dd][c]: a = h-axis, dd = d-slice, c: 0 = w0-1, 1..4 = w0..w0+3, 5 = w0+4
    float v[3][4][6];
#pragma unroll
    for (int a = 0; a < 3; ++a) {
#pragma unroll
        for (int dd = 0; dd < 4; ++dd) {
            const float* ph = base + (size_t)dd * HWc + (size_t)hz[a] * Wn;
            const float4 q = *reinterpret_cast<const float4*>(ph + w0);
            v[a][dd][0] = ph[wl];
            v[a][dd][1] = q.x;
            v[a][dd][2] = q.y;
            v[a][dd][3] = q.z;
            v[a][dd][4] = q.w;
            v[a][dd][5] = ph[wr];
        }
    }

    // d = 0 and d = 3: trivial (strict NMS impossible vs replicated self)
    {
        const size_t sp0 = (size_t)h * Wn + (size_t)w0;
        *reinterpret_cast<float4*>(cb + sp0)            = cz0;
        *reinterpret_cast<float4*>(cb + DHWc + sp0)     = cx;
        *reinterpret_cast<float4*>(cb + 2 * DHWc + sp0) = cy;
        *reinterpret_cast<float4*>(yb + sp0)            = make_float4(v[1][0][1], v[1][0][2], v[1][0][3], v[1][0][4]);
        const size_t sp3 = 3 * (size_t)HWc + sp0;
        *reinterpret_cast<float4*>(cb + sp3)            = cz3;
        *reinterpret_cast<float4*>(cb + DHWc + sp3)     = cx;
        *reinterpret_cast<float4*>(cb + 2 * DHWc + sp3) = cy;
        *reinterpret_cast<float4*>(yb + sp3)            = make_float4(v[1][3][1], v[1][3][2], v[1][3][3], v[1][3][4]);
    }

    // d = 1, 2: full NMS + quadratic interpolation
#pragma unroll
    for (int d = 1; d <= 2; ++d) {
        const int s0 = d - 1;
        const int s2 = d + 1;
        float colNC[6], cmax[6];
#pragma unroll
        for (int c = 0; c < 6; ++c) {
            float m = v[0][s0][c];
            m = fmaxf(m, v[1][s0][c]);
            m = fmaxf(m, v[2][s0][c]);
            m = fmaxf(m, v[0][d][c]);
            m = fmaxf(m, v[2][d][c]);
            m = fmaxf(m, v[0][s2][c]);
            m = fmaxf(m, v[1][s2][c]);
            m = fmaxf(m, v[2][s2][c]);
            colNC[c] = m;
            cmax[c] = fmaxf(m, v[1][d][c]);
        }

        float outz[4], outx[4], outy[4], outv[4];
#pragma unroll
        for (int j = 0; j < 4; ++j) {
            const int cc = j + 1;
            const float xc = v[1][d][cc];
            const float m = fmaxf(fmaxf(cmax[cc - 1], cmax[cc + 1]), fmaxf(colNC[cc], 0.0f));
            const bool nms = xc > m;

            const float gx  = 0.5f * (v[1][d][cc + 1] - v[1][d][cc - 1]);
            const float gy  = 0.5f * (v[2][d][cc] - v[0][d][cc]);
            const float gs  = 0.5f * (v[1][s2][cc] - v[1][s0][cc]);
            const float dxx = v[1][d][cc + 1] - 2.0f * xc + v[1][d][cc - 1];
            const float dyy = v[2][d][cc] - 2.0f * xc + v[0][d][cc];
            const float dss = v[1][s2][cc] - 2.0f * xc + v[1][s0][cc];
            const float dxy =  0.25f * (v[2][d][cc + 1] - v[2][d][cc - 1] - v[0][d][cc + 1] + v[0][d][cc - 1]);
            const float dys = -0.25f * (v[2][s2][cc] - v[0][s2][cc] - v[2][s0][cc] + v[0][s0][cc]);
            const float dxs = -0.25f * (v[1][s2][cc + 1] - v[1][s2][cc - 1] - v[1][s0][cc + 1] + v[1][s0][cc - 1]);

            const float cf00 = dyy * dss - dys * dys;
            const float cf01 = dxy * dss - dys * dxs;
            const float cf02 = dxy * dys - dyy * dxs;
            const float det  = dxx * cf00 - dxy * cf01 + dxs * cf02;
            const bool solved = fabsf(det) > 0.0f;
            const float sd = solved ? det : 1.0f;

            const float t0 = gy * dss - dys * gs;
            const float sx = (gx * cf00 - dxy * t0 + dxs * (gy * dys - dyy * gs)) / sd;
            const float sy = (dxx * t0 - gx * cf01 + dxs * (dxy * gs - gy * dxs)) / sd;
            const float ss = (dxx * (dyy * gs - gy * dys) - dxy * (dxy * gs - gy * dxs) + gx * cf02) / sd;

            const bool valid = nms && solved;
            float dxv = valid ? -sx : 0.0f;
            float dyv = valid ? -sy : 0.0f;
            float dsv = valid ? -ss : 0.0f;
            const float mx = fmaxf(fmaxf(fabsf(dxv), fabsf(dyv)), fabsf(dsv));
            if (mx > 0.7f) { dxv = 0.0f; dyv = 0.0f; dsv = 0.0f; }

            const float dy_ = 0.5f * (gx * dxv + gy * dyv + gs * dsv);
            float y = xc + dy_;
            if (valid) y += BONUS;

            outz[j] = (float)d + dsv;
            outx[j] = (float)(w0 + j) + dxv;
            outy[j] = (float)h + dyv;
            outv[j] = y;
        }

        const size_t sp = (size_t)d * HWc + (size_t)h * Wn + (size_t)w0;
        *reinterpret_cast<float4*>(cb + sp)            = make_float4(outz[0], outz[1], outz[2], outz[3]);
        *reinterpret_cast<float4*>(cb + DHWc + sp)     = make_float4(outx[0], outx[1], outx[2], outx[3]);
        *reinterpret_cast<float4*>(cb + 2 * DHWc + sp) = make_float4(outy[0], outy[1], outy[2], outy[3]);
        *reinterpret_cast<float4*>(yb + sp)            = make_float4(outv[0], outv[1], outv[2], outv[3]);
    }
}

extern "C" void kernel_launch(void* const* d_in, const int* in_sizes, int n_in,
                              void* d_out, int out_size, void* d_ws, size_t ws_size,
                              hipStream_t stream) {
    const float* x = (const float*)d_in[0];
    float* out = (float*)d_out;
    float* coords = out;                          // (B,1,3,D,H,W) flat
    float* ymaxp  = out + (size_t)Bn * 3 * DHWc;  // (B,1,D,H,W) flat
    cqi3d<<<dim3(Hn * Bn), dim3(192, 1, 1), 0, stream>>>(x, coords, ymaxp);
}